// Round 7
// baseline (225.060 us; speedup 1.0000x reference)
//
#include <hip/hip_runtime.h>

#define D 64
#define SH 9            // 512 cols per bucket
#define CPB 512         // 1<<SH
#define CH 4096         // edges per block in bucket kernels
#define MAXNB 256       // fast path supports N <= 131072

// ---------- deterministic bucket-sort path (no cross-block atomics) ----------

// per-(bucket, block) counts -> cmat[b*NBLK + blk]
__global__ __launch_bounds__(256) void count_kernel(
    const int* __restrict__ es, int* __restrict__ cmat,
    int NB, int NBLK, int E) {
  __shared__ int hist[MAXNB];
  int t = threadIdx.x;
  hist[t] = 0;
  __syncthreads();
  int base_e = blockIdx.x * CH;
#pragma unroll
  for (int j = 0; j < 16; j++) {
    int e = base_e + t + j * 256;
    if (e < E) atomicAdd(&hist[es[e] >> SH], 1);
  }
  __syncthreads();
  if (t < NB) cmat[t * NBLK + blockIdx.x] = hist[t];
}

// single block: global exclusive scan of cmat (bucket-major), in place.
// Also emits bbase[b] (bucket starts) and sentinels.
__global__ __launch_bounds__(1024) void scan_kernel(
    int* __restrict__ cmat, int* __restrict__ bbase,
    int* __restrict__ offsets, int NB, int NBLK, int N, int E) {
  __shared__ int lds[1024];
  int t = threadIdx.x;
  int M = NB * NBLK;
  int per = (M + 1023) >> 10;
  int lo = t * per, hi = min(M, lo + per);
  int s = 0;
  for (int i = lo; i < hi; i++) s += cmat[i];
  lds[t] = s;
  __syncthreads();
  for (int off = 1; off < 1024; off <<= 1) {
    int v = (t >= off) ? lds[t - off] : 0;
    __syncthreads();
    lds[t] += v;
    __syncthreads();
  }
  int run = (t == 0) ? 0 : lds[t - 1];
  for (int i = lo; i < hi; i++) {
    int c = cmat[i];
    cmat[i] = run;
    if (i % NBLK == 0) bbase[i / NBLK] = run;
    run += c;
  }
  if (t == 0) { bbase[NB] = E; offsets[N] = E; }
}

// stage in LDS by local rank, then write coalesced runs to exact
// deterministic destinations (cmat gives this block's base per bucket).
__global__ __launch_bounds__(256) void scatter_kernel(
    const int* __restrict__ es, const int* __restrict__ cmat,
    int* __restrict__ packed, int NB, int NBLK, int E) {
  __shared__ int hist[MAXNB];
  __shared__ int lstart[MAXNB];
  __shared__ int gbase[MAXNB];
  __shared__ int cursor[MAXNB];
  __shared__ int sctmp[256];
  __shared__ int staged[CH];
  __shared__ int bidl[CH];
  int t = threadIdx.x;
  hist[t] = 0;
  __syncthreads();
  int base_e = blockIdx.x * CH;
  int c[16], r[16];
#pragma unroll
  for (int j = 0; j < 16; j++) {
    int e = base_e + t + j * 256;
    if (e < E) {
      c[j] = es[e];
      r[j] = es[E + e];
      atomicAdd(&hist[c[j] >> SH], 1);
    } else {
      c[j] = -1;
    }
  }
  __syncthreads();
  // exclusive scan over 256 buckets (thread t owns bucket t)
  int v = hist[t];
  sctmp[t] = v;
  __syncthreads();
  for (int off = 1; off < 256; off <<= 1) {
    int val = (t >= off) ? sctmp[t - off] : 0;
    __syncthreads();
    sctmp[t] += val;
    __syncthreads();
  }
  int excl = sctmp[t] - v;
  lstart[t] = excl;
  cursor[t] = excl;
  if (t < NB) gbase[t] = cmat[t * NBLK + blockIdx.x];
  __syncthreads();
#pragma unroll
  for (int j = 0; j < 16; j++) {
    if (c[j] >= 0) {
      int b = c[j] >> SH;
      int rank = atomicAdd(&cursor[b], 1);
      staged[rank] = (r[j] << SH) | (c[j] & (CPB - 1));
      bidl[rank] = b;
    }
  }
  __syncthreads();
  int nloc = min(CH, E - base_e);
  for (int i = t; i < nloc; i += 256) {
    int b = bidl[i];
    packed[gbase[b] + (i - lstart[b])] = staged[i];
  }
}

// one block per bucket: counting-sort run by exact column -> CSR
__global__ __launch_bounds__(256) void sort_cols(
    const int* __restrict__ packed, const int* __restrict__ bbase,
    int* __restrict__ offsets, int* __restrict__ sorted_rows, int N) {
  __shared__ int cnt[CPB];
  __shared__ int sctmp[256];
  __shared__ int cur[CPB];
  int b = blockIdx.x;
  int t = threadIdx.x;
  int s = bbase[b], e = bbase[b + 1];
  cnt[t] = 0;
  cnt[t + 256] = 0;
  __syncthreads();
  for (int i = s + t; i < e; i += 256) atomicAdd(&cnt[packed[i] & (CPB - 1)], 1);
  __syncthreads();
  int c0 = cnt[2 * t], c1 = cnt[2 * t + 1];
  int pair = c0 + c1;
  sctmp[t] = pair;
  __syncthreads();
  for (int off = 1; off < 256; off <<= 1) {
    int val = (t >= off) ? sctmp[t - off] : 0;
    __syncthreads();
    sctmp[t] += val;
    __syncthreads();
  }
  int excl = sctmp[t] - pair;
  cur[2 * t] = excl;
  cur[2 * t + 1] = excl + c0;
  int gc0 = (b << SH) + 2 * t;
  if (gc0 < N) offsets[gc0] = s + excl;
  if (gc0 + 1 < N) offsets[gc0 + 1] = s + excl + c0;
  __syncthreads();
  for (int i = s + t; i < e; i += 256) {
    int p = packed[i];
    int cc = p & (CPB - 1);
    int rank = atomicAdd(&cur[cc], 1);
    sorted_rows[s + rank] = p >> SH;
  }
}

// one 64-lane wave per node; 4 lane-groups of 16, each group owns one edge,
// lane reads one float4 of the 64-float row; 16 edges in flight (4 accs)
__global__ __launch_bounds__(256) void node_reduce(
    const float4* __restrict__ x4, const int* __restrict__ sorted_rows,
    const int* __restrict__ offsets, float* __restrict__ out, int N) {
  int gid = blockIdx.x * 256 + threadIdx.x;
  int node = gid >> 6;
  if (node >= N) return;
  int lane = threadIdx.x & 63;
  int eg = lane >> 4;
  int d16 = lane & 15;
  int start = offsets[node];
  int cnt = offsets[node + 1] - start;
  float4 a0 = make_float4(0.f, 0.f, 0.f, 0.f);
  float4 a1 = make_float4(0.f, 0.f, 0.f, 0.f);
  float4 a2 = make_float4(0.f, 0.f, 0.f, 0.f);
  float4 a3 = make_float4(0.f, 0.f, 0.f, 0.f);
  for (int base = 0; base < cnt; base += 16) {
    int k0 = base + eg;
    int k1 = base + 4 + eg;
    int k2 = base + 8 + eg;
    int k3 = base + 12 + eg;
    int r0 = (k0 < cnt) ? sorted_rows[start + k0] : -1;
    int r1 = (k1 < cnt) ? sorted_rows[start + k1] : -1;
    int r2 = (k2 < cnt) ? sorted_rows[start + k2] : -1;
    int r3 = (k3 < cnt) ? sorted_rows[start + k3] : -1;
    if (r0 >= 0) { float4 v = x4[(size_t)r0 * 16 + d16];
      a0.x += v.x; a0.y += v.y; a0.z += v.z; a0.w += v.w; }
    if (r1 >= 0) { float4 v = x4[(size_t)r1 * 16 + d16];
      a1.x += v.x; a1.y += v.y; a1.z += v.z; a1.w += v.w; }
    if (r2 >= 0) { float4 v = x4[(size_t)r2 * 16 + d16];
      a2.x += v.x; a2.y += v.y; a2.z += v.z; a2.w += v.w; }
    if (r3 >= 0) { float4 v = x4[(size_t)r3 * 16 + d16];
      a3.x += v.x; a3.y += v.y; a3.z += v.z; a3.w += v.w; }
  }
  a0.x += a1.x + a2.x + a3.x;
  a0.y += a1.y + a2.y + a3.y;
  a0.z += a1.z + a2.z + a3.z;
  a0.w += a1.w + a2.w + a3.w;
  a0.x += __shfl_xor(a0.x, 16); a0.y += __shfl_xor(a0.y, 16);
  a0.z += __shfl_xor(a0.z, 16); a0.w += __shfl_xor(a0.w, 16);
  a0.x += __shfl_xor(a0.x, 32); a0.y += __shfl_xor(a0.y, 32);
  a0.z += __shfl_xor(a0.z, 32); a0.w += __shfl_xor(a0.w, 32);
  float4* o4 = (float4*)(out + (size_t)node * 2 * D);
  if (eg == 0) {
    float inv = 1.0f / (float)(cnt > 0 ? cnt : 1);
    a0.x *= inv; a0.y *= inv; a0.z *= inv; a0.w *= inv;
    o4[d16] = a0;
  } else if (eg == 1) {
    float4 v = (cnt > 0) ? x4[(size_t)node * 16 + d16]
                         : make_float4(0.f, 0.f, 0.f, 0.f);
    o4[16 + d16] = v;
  }
}

// ---------- fallback atomic path (only if fast path inapplicable) ----------

__global__ __launch_bounds__(256) void edge_scatter_atomic(
    const int* __restrict__ es, const float* __restrict__ x,
    float* __restrict__ out, int* __restrict__ count, int E) {
  int gid = blockIdx.x * blockDim.x + threadIdx.x;
  int e = gid >> 6;
  int lane = gid & 63;
  if (e >= E) return;
  int c = es[e];
  int r = es[E + e];
  if (lane == 0) atomicAdd(&count[c], 1);
  float v = x[(size_t)r * D + lane];
  unsafeAtomicAdd(&out[(size_t)c * 2 * D + lane], v);
}

__global__ __launch_bounds__(256) void finalize_atomic(
    const float* __restrict__ x, float* __restrict__ out,
    const int* __restrict__ count, int N) {
  int gid = blockIdx.x * blockDim.x + threadIdx.x;
  int node = gid >> 5;
  int j4 = gid & 31;
  if (node >= N) return;
  int cnt = count[node];
  float4* out4 = (float4*)(out + (size_t)node * 2 * D);
  if (j4 < 16) {
    float4 s = out4[j4];
    float inv = 1.0f / (float)(cnt > 0 ? cnt : 1);
    s.x *= inv; s.y *= inv; s.z *= inv; s.w *= inv;
    out4[j4] = s;
  } else {
    float4 v;
    if (cnt > 0) {
      const float4* x4 = (const float4*)(x + (size_t)node * D);
      v = x4[j4 - 16];
    } else {
      v = make_float4(0.f, 0.f, 0.f, 0.f);
    }
    out4[j4] = v;
  }
}

extern "C" void kernel_launch(void* const* d_in, const int* in_sizes, int n_in,
                              void* d_out, int out_size, void* d_ws, size_t ws_size,
                              hipStream_t stream) {
  const float* x = (const float*)d_in[0];
  const int* es = (const int*)d_in[1];
  int N = in_sizes[0] / D;
  int E = in_sizes[1] / 2;
  float* out = (float*)d_out;

  int NB = (N + CPB - 1) >> SH;
  int NBLK = (E + CH - 1) / CH;
  size_t need = ((size_t)NB * NBLK + (NB + 1) + ((size_t)N + 1) +
                 2 * (size_t)E) * sizeof(int);
  if (NB > MAXNB || ws_size < need) {
    int* count = (int*)d_ws;
    hipMemsetAsync(count, 0, (size_t)N * sizeof(int), stream);
    hipMemsetAsync(out, 0, (size_t)N * 2 * D * sizeof(float), stream);
    long long t1 = (long long)E * 64;
    edge_scatter_atomic<<<(int)((t1 + 255) / 256), 256, 0, stream>>>(es, x, out, count, E);
    long long t2 = (long long)N * 32;
    finalize_atomic<<<(int)((t2 + 255) / 256), 256, 0, stream>>>(x, out, count, N);
    return;
  }

  int* ws = (int*)d_ws;
  int* cmat = ws;                         // NB*NBLK
  int* bbase = cmat + (size_t)NB * NBLK;  // NB+1
  int* offsets = bbase + NB + 1;          // N+1
  int* packed = offsets + N + 1;          // E
  int* sorted_rows = packed + E;          // E

  count_kernel<<<NBLK, 256, 0, stream>>>(es, cmat, NB, NBLK, E);
  scan_kernel<<<1, 1024, 0, stream>>>(cmat, bbase, offsets, NB, NBLK, N, E);
  scatter_kernel<<<NBLK, 256, 0, stream>>>(es, cmat, packed, NB, NBLK, E);
  sort_cols<<<NB, 256, 0, stream>>>(packed, bbase, offsets, sorted_rows, N);

  long long rt = (long long)N * 64;
  node_reduce<<<(int)((rt + 255) / 256), 256, 0, stream>>>(
      (const float4*)x, sorted_rows, offsets, out, N);
}

// Round 8
// 162.204 us; speedup vs baseline: 1.3875x; 1.3875x over previous
//
#include <hip/hip_runtime.h>

#define D 64
#define SH 9            // 512 cols per bucket
#define CPB 512         // 1<<SH
#define CH 4096         // edges per block in bucket kernels
#define MAXNB 256       // fast path supports N <= 131072

// ---------- deterministic bucket-sort path (no cross-block atomics) ----------

// per-(bucket, block) counts -> cmat[b*NBLK + blk]
__global__ __launch_bounds__(256) void count_kernel(
    const int* __restrict__ es, int* __restrict__ cmat,
    int NB, int NBLK, int E) {
  __shared__ int hist[MAXNB];
  int t = threadIdx.x;
  hist[t] = 0;
  __syncthreads();
  int base_e = blockIdx.x * CH;
#pragma unroll
  for (int j = 0; j < 16; j++) {
    int e = base_e + t + j * 256;
    if (e < E) atomicAdd(&hist[es[e] >> SH], 1);
  }
  __syncthreads();
  if (t < NB) cmat[t * NBLK + blockIdx.x] = hist[t];
}

// hierarchical scan over flat cmat[0..M): P1 local scan (1024/block)
__global__ __launch_bounds__(256) void scanP1(
    int* __restrict__ cmat, int* __restrict__ bsums, int M) {
  __shared__ int lds[256];
  int t = threadIdx.x;
  int base = blockIdx.x * 1024 + t * 4;
  int v[4], s = 0;
#pragma unroll
  for (int i = 0; i < 4; i++) {
    v[i] = (base + i < M) ? cmat[base + i] : 0;
    s += v[i];
  }
  lds[t] = s;
  __syncthreads();
  for (int off = 1; off < 256; off <<= 1) {
    int val = (t >= off) ? lds[t - off] : 0;
    __syncthreads();
    lds[t] += val;
    __syncthreads();
  }
  int run = lds[t] - s;
#pragma unroll
  for (int i = 0; i < 4; i++) {
    if (base + i < M) cmat[base + i] = run;
    run += v[i];
  }
  if (t == 255) bsums[blockIdx.x] = lds[255];
}

// P2: single block scans <=256 block sums -> exclusive bases; sentinels
__global__ __launch_bounds__(256) void scanP2(
    int* __restrict__ bsums, int* __restrict__ bbase,
    int* __restrict__ offsets, int nb, int NB, int N, int E) {
  __shared__ int lds[256];
  int t = threadIdx.x;
  int v = (t < nb) ? bsums[t] : 0;
  lds[t] = v;
  __syncthreads();
  for (int off = 1; off < 256; off <<= 1) {
    int val = (t >= off) ? lds[t - off] : 0;
    __syncthreads();
    lds[t] += val;
    __syncthreads();
  }
  if (t < nb) bsums[t] = lds[t] - v;
  if (t == 0) { bbase[NB] = E; offsets[N] = E; }
}

// P3: add block base; extract bucket starts where i % NBLK == 0
__global__ __launch_bounds__(256) void scanP3(
    int* __restrict__ cmat, const int* __restrict__ bsums,
    int* __restrict__ bbase, int M, int NBLK) {
  int t = threadIdx.x;
  int add = bsums[blockIdx.x];
  int base = blockIdx.x * 1024 + t * 4;
#pragma unroll
  for (int i = 0; i < 4; i++) {
    int idx = base + i;
    if (idx < M) {
      int v = cmat[idx] + add;
      cmat[idx] = v;
      if (idx % NBLK == 0) bbase[idx / NBLK] = v;
    }
  }
}

// stage in LDS by local rank, then write coalesced runs to exact
// deterministic destinations (cmat gives this block's base per bucket).
__global__ __launch_bounds__(256) void scatter_kernel(
    const int* __restrict__ es, const int* __restrict__ cmat,
    int* __restrict__ packed, int NB, int NBLK, int E) {
  __shared__ int hist[MAXNB];
  __shared__ int lstart[MAXNB];
  __shared__ int gbase[MAXNB];
  __shared__ int cursor[MAXNB];
  __shared__ int sctmp[256];
  __shared__ int staged[CH];
  __shared__ int bidl[CH];
  int t = threadIdx.x;
  hist[t] = 0;
  __syncthreads();
  int base_e = blockIdx.x * CH;
  int c[16], r[16];
#pragma unroll
  for (int j = 0; j < 16; j++) {
    int e = base_e + t + j * 256;
    if (e < E) {
      c[j] = es[e];
      r[j] = es[E + e];
      atomicAdd(&hist[c[j] >> SH], 1);
    } else {
      c[j] = -1;
    }
  }
  __syncthreads();
  // exclusive scan over 256 buckets (thread t owns bucket t)
  int v = hist[t];
  sctmp[t] = v;
  __syncthreads();
  for (int off = 1; off < 256; off <<= 1) {
    int val = (t >= off) ? sctmp[t - off] : 0;
    __syncthreads();
    sctmp[t] += val;
    __syncthreads();
  }
  int excl = sctmp[t] - v;
  lstart[t] = excl;
  cursor[t] = excl;
  if (t < NB) gbase[t] = cmat[t * NBLK + blockIdx.x];
  __syncthreads();
#pragma unroll
  for (int j = 0; j < 16; j++) {
    if (c[j] >= 0) {
      int b = c[j] >> SH;
      int rank = atomicAdd(&cursor[b], 1);
      staged[rank] = (r[j] << SH) | (c[j] & (CPB - 1));
      bidl[rank] = b;
    }
  }
  __syncthreads();
  int nloc = min(CH, E - base_e);
  for (int i = t; i < nloc; i += 256) {
    int b = bidl[i];
    packed[gbase[b] + (i - lstart[b])] = staged[i];
  }
}

// one block per bucket: counting-sort run by exact column -> CSR
__global__ __launch_bounds__(256) void sort_cols(
    const int* __restrict__ packed, const int* __restrict__ bbase,
    int* __restrict__ offsets, int* __restrict__ sorted_rows, int N) {
  __shared__ int cnt[CPB];
  __shared__ int sctmp[256];
  __shared__ int cur[CPB];
  int b = blockIdx.x;
  int t = threadIdx.x;
  int s = bbase[b], e = bbase[b + 1];
  cnt[t] = 0;
  cnt[t + 256] = 0;
  __syncthreads();
  for (int i = s + t; i < e; i += 256) atomicAdd(&cnt[packed[i] & (CPB - 1)], 1);
  __syncthreads();
  int c0 = cnt[2 * t], c1 = cnt[2 * t + 1];
  int pair = c0 + c1;
  sctmp[t] = pair;
  __syncthreads();
  for (int off = 1; off < 256; off <<= 1) {
    int val = (t >= off) ? sctmp[t - off] : 0;
    __syncthreads();
    sctmp[t] += val;
    __syncthreads();
  }
  int excl = sctmp[t] - pair;
  cur[2 * t] = excl;
  cur[2 * t + 1] = excl + c0;
  int gc0 = (b << SH) + 2 * t;
  if (gc0 < N) offsets[gc0] = s + excl;
  if (gc0 + 1 < N) offsets[gc0 + 1] = s + excl + c0;
  __syncthreads();
  for (int i = s + t; i < e; i += 256) {
    int p = packed[i];
    int cc = p & (CPB - 1);
    int rank = atomicAdd(&cur[cc], 1);
    sorted_rows[s + rank] = p >> SH;
  }
}

// one 64-lane wave per node; 4 lane-groups of 16, each group owns one edge,
// lane reads one float4 of the 64-float row; 16 edges in flight (4 accs)
__global__ __launch_bounds__(256) void node_reduce(
    const float4* __restrict__ x4, const int* __restrict__ sorted_rows,
    const int* __restrict__ offsets, float* __restrict__ out, int N) {
  int gid = blockIdx.x * 256 + threadIdx.x;
  int node = gid >> 6;
  if (node >= N) return;
  int lane = threadIdx.x & 63;
  int eg = lane >> 4;
  int d16 = lane & 15;
  int start = offsets[node];
  int cnt = offsets[node + 1] - start;
  float4 a0 = make_float4(0.f, 0.f, 0.f, 0.f);
  float4 a1 = make_float4(0.f, 0.f, 0.f, 0.f);
  float4 a2 = make_float4(0.f, 0.f, 0.f, 0.f);
  float4 a3 = make_float4(0.f, 0.f, 0.f, 0.f);
  for (int base = 0; base < cnt; base += 16) {
    int k0 = base + eg;
    int k1 = base + 4 + eg;
    int k2 = base + 8 + eg;
    int k3 = base + 12 + eg;
    int r0 = (k0 < cnt) ? sorted_rows[start + k0] : -1;
    int r1 = (k1 < cnt) ? sorted_rows[start + k1] : -1;
    int r2 = (k2 < cnt) ? sorted_rows[start + k2] : -1;
    int r3 = (k3 < cnt) ? sorted_rows[start + k3] : -1;
    if (r0 >= 0) { float4 v = x4[(size_t)r0 * 16 + d16];
      a0.x += v.x; a0.y += v.y; a0.z += v.z; a0.w += v.w; }
    if (r1 >= 0) { float4 v = x4[(size_t)r1 * 16 + d16];
      a1.x += v.x; a1.y += v.y; a1.z += v.z; a1.w += v.w; }
    if (r2 >= 0) { float4 v = x4[(size_t)r2 * 16 + d16];
      a2.x += v.x; a2.y += v.y; a2.z += v.z; a2.w += v.w; }
    if (r3 >= 0) { float4 v = x4[(size_t)r3 * 16 + d16];
      a3.x += v.x; a3.y += v.y; a3.z += v.z; a3.w += v.w; }
  }
  a0.x += a1.x + a2.x + a3.x;
  a0.y += a1.y + a2.y + a3.y;
  a0.z += a1.z + a2.z + a3.z;
  a0.w += a1.w + a2.w + a3.w;
  a0.x += __shfl_xor(a0.x, 16); a0.y += __shfl_xor(a0.y, 16);
  a0.z += __shfl_xor(a0.z, 16); a0.w += __shfl_xor(a0.w, 16);
  a0.x += __shfl_xor(a0.x, 32); a0.y += __shfl_xor(a0.y, 32);
  a0.z += __shfl_xor(a0.z, 32); a0.w += __shfl_xor(a0.w, 32);
  float4* o4 = (float4*)(out + (size_t)node * 2 * D);
  if (eg == 0) {
    float inv = 1.0f / (float)(cnt > 0 ? cnt : 1);
    a0.x *= inv; a0.y *= inv; a0.z *= inv; a0.w *= inv;
    o4[d16] = a0;
  } else if (eg == 1) {
    float4 v = (cnt > 0) ? x4[(size_t)node * 16 + d16]
                         : make_float4(0.f, 0.f, 0.f, 0.f);
    o4[16 + d16] = v;
  }
}

// ---------- fallback atomic path (only if fast path inapplicable) ----------

__global__ __launch_bounds__(256) void edge_scatter_atomic(
    const int* __restrict__ es, const float* __restrict__ x,
    float* __restrict__ out, int* __restrict__ count, int E) {
  int gid = blockIdx.x * blockDim.x + threadIdx.x;
  int e = gid >> 6;
  int lane = gid & 63;
  if (e >= E) return;
  int c = es[e];
  int r = es[E + e];
  if (lane == 0) atomicAdd(&count[c], 1);
  float v = x[(size_t)r * D + lane];
  unsafeAtomicAdd(&out[(size_t)c * 2 * D + lane], v);
}

__global__ __launch_bounds__(256) void finalize_atomic(
    const float* __restrict__ x, float* __restrict__ out,
    const int* __restrict__ count, int N) {
  int gid = blockIdx.x * blockDim.x + threadIdx.x;
  int node = gid >> 5;
  int j4 = gid & 31;
  if (node >= N) return;
  int cnt = count[node];
  float4* out4 = (float4*)(out + (size_t)node * 2 * D);
  if (j4 < 16) {
    float4 s = out4[j4];
    float inv = 1.0f / (float)(cnt > 0 ? cnt : 1);
    s.x *= inv; s.y *= inv; s.z *= inv; s.w *= inv;
    out4[j4] = s;
  } else {
    float4 v;
    if (cnt > 0) {
      const float4* x4 = (const float4*)(x + (size_t)node * D);
      v = x4[j4 - 16];
    } else {
      v = make_float4(0.f, 0.f, 0.f, 0.f);
    }
    out4[j4] = v;
  }
}

extern "C" void kernel_launch(void* const* d_in, const int* in_sizes, int n_in,
                              void* d_out, int out_size, void* d_ws, size_t ws_size,
                              hipStream_t stream) {
  const float* x = (const float*)d_in[0];
  const int* es = (const int*)d_in[1];
  int N = in_sizes[0] / D;
  int E = in_sizes[1] / 2;
  float* out = (float*)d_out;

  int NB = (N + CPB - 1) >> SH;
  int NBLK = (E + CH - 1) / CH;
  int M = NB * NBLK;
  int nb2 = (M + 1023) / 1024;  // scan blocks
  size_t need = ((size_t)M + 256 + (NB + 1) + ((size_t)N + 1) +
                 2 * (size_t)E) * sizeof(int);
  if (NB > MAXNB || nb2 > 256 || ws_size < need) {
    int* count = (int*)d_ws;
    hipMemsetAsync(count, 0, (size_t)N * sizeof(int), stream);
    hipMemsetAsync(out, 0, (size_t)N * 2 * D * sizeof(float), stream);
    long long t1 = (long long)E * 64;
    edge_scatter_atomic<<<(int)((t1 + 255) / 256), 256, 0, stream>>>(es, x, out, count, E);
    long long t2 = (long long)N * 32;
    finalize_atomic<<<(int)((t2 + 255) / 256), 256, 0, stream>>>(x, out, count, N);
    return;
  }

  int* ws = (int*)d_ws;
  int* cmat = ws;                         // M
  int* bsums = cmat + M;                  // 256
  int* bbase = bsums + 256;               // NB+1
  int* offsets = bbase + NB + 1;          // N+1
  int* packed = offsets + N + 1;          // E
  int* sorted_rows = packed + E;          // E

  count_kernel<<<NBLK, 256, 0, stream>>>(es, cmat, NB, NBLK, E);
  scanP1<<<nb2, 256, 0, stream>>>(cmat, bsums, M);
  scanP2<<<1, 256, 0, stream>>>(bsums, bbase, offsets, nb2, NB, N, E);
  scanP3<<<nb2, 256, 0, stream>>>(cmat, bsums, bbase, M, NBLK);
  scatter_kernel<<<NBLK, 256, 0, stream>>>(es, cmat, packed, NB, NBLK, E);
  sort_cols<<<NB, 256, 0, stream>>>(packed, bbase, offsets, sorted_rows, N);

  long long rt = (long long)N * 64;
  node_reduce<<<(int)((rt + 255) / 256), 256, 0, stream>>>(
      (const float4*)x, sorted_rows, offsets, out, N);
}